// Round 2
// baseline (1588.651 us; speedup 1.0000x reference)
//
#include <hip/hip_runtime.h>
#include <hip/hip_bf16.h>
#include <stdint.h>

#define T_TOKENS 8192
#define D_DIM    1024
#define F_DIM    4096
#define NE       8
#define MAXTILES 136

typedef unsigned short u16;
typedef __attribute__((ext_vector_type(8))) __bf16 bf16x8;
typedef __attribute__((ext_vector_type(4))) float  f32x4;

// ---------- helpers ----------
__device__ __forceinline__ u16 f2bf(float f) {
    __hip_bfloat16 h = __float2bfloat16(f);
    return *reinterpret_cast<u16*>(&h);
}

__device__ __forceinline__ void gl_lds16(const void* g, void* l) {
    __builtin_amdgcn_global_load_lds(
        (const __attribute__((address_space(1))) uint32_t*)g,
        (__attribute__((address_space(3))) uint32_t*)l, 16, 0, 0);
}

// ---------- ctrl layout (int indices into ws base) ----------
// [0..7] counts  [8..15] cursor  [16..24] off  [32] n_tiles
// [64..199] tile_e  [256..391] tile_m0

// ---------- kernel 1: router ----------
__global__ __launch_bounds__(256) void k_router(
    const float* __restrict__ x, const float* __restrict__ gate_w,
    float* __restrict__ logits_out, int* __restrict__ ti,
    float* __restrict__ tw, int* __restrict__ ctrl)
{
    __shared__ float gw[NE * D_DIM];
    int tid = threadIdx.x;
    for (int i = tid; i < NE * D_DIM; i += 256) gw[i] = gate_w[i];
    __syncthreads();

    int wave = tid >> 6, lane = tid & 63;
    int t = blockIdx.x * 4 + wave;

    const float* xr = x + (size_t)t * D_DIM;
    float xv[16];
#pragma unroll
    for (int i = 0; i < 16; i++) xv[i] = xr[i * 64 + lane];

    float acc[NE];
#pragma unroll
    for (int e = 0; e < NE; e++) {
        float s = 0.f;
#pragma unroll
        for (int i = 0; i < 16; i++) s += xv[i] * gw[e * D_DIM + i * 64 + lane];
        for (int off = 32; off; off >>= 1) s += __shfl_down(s, off, 64);
        acc[e] = s;
    }

    if (lane == 0) {
#pragma unroll
        for (int e = 0; e < NE; e++) logits_out[t * NE + e] = acc[e];
        int i0 = 0; float v0 = acc[0];
        for (int e = 1; e < NE; e++) if (acc[e] > v0) { v0 = acc[e]; i0 = e; }
        int i1 = -1; float v1 = -3.0e38f;
        for (int e = 0; e < NE; e++) if (e != i0 && acc[e] > v1) { v1 = acc[e]; i1 = e; }
        float e1 = expf(v1 - v0);
        float s  = 1.f + e1;
        float w0 = 1.f / s, w1 = e1 / s;
        ti[t * 2 + 0] = i0; ti[t * 2 + 1] = i1;
        tw[t * 2 + 0] = w0; tw[t * 2 + 1] = w1;
        atomicAdd(&ctrl[i0], 1);
        atomicAdd(&ctrl[i1], 1);
    }
}

// ---------- kernel 2: plan ----------
__global__ void k_plan(int* __restrict__ ctrl)
{
    if (threadIdx.x != 0 || blockIdx.x != 0) return;
    int* counts  = ctrl;
    int* off     = ctrl + 16;
    int* tile_e  = ctrl + 64;
    int* tile_m0 = ctrl + 256;
    int o = 0, nt = 0;
    for (int e = 0; e < NE; e++) {
        off[e] = o;
        int c = counts[e];
        int tcnt = (c + 127) >> 7;
        for (int j = 0; j < tcnt; j++) { tile_e[nt] = e; tile_m0[nt] = o + j * 128; nt++; }
        o += tcnt << 7;
    }
    off[NE] = o;
    ctrl[32] = nt;
}

// ---------- kernel 3: scatter ----------
__global__ __launch_bounds__(256) void k_scatter(
    const int* __restrict__ ti, const float* __restrict__ tw,
    int* __restrict__ ctrl, int* __restrict__ pair_token, float* __restrict__ pair_w)
{
    int t = blockIdx.x * 256 + threadIdx.x;
    if (t >= T_TOKENS) return;
    int* off    = ctrl + 16;
    int* cursor = ctrl + 8;
#pragma unroll
    for (int k = 0; k < 2; k++) {
        int e = ti[t * 2 + k];
        int slot = off[e] + atomicAdd(&cursor[e], 1);
        pair_token[slot] = t;
        pair_w[slot] = tw[t * 2 + k];
    }
}

// ---------- kernel 4: x -> bf16 ----------
__global__ __launch_bounds__(256) void k_cvt_x(
    const float* __restrict__ x, u16* __restrict__ xb)
{
    size_t i = ((size_t)blockIdx.x * 256 + threadIdx.x) * 4;
    float4 v = *(const float4*)(x + i);
    ushort4 o;
    o.x = f2bf(v.x); o.y = f2bf(v.y); o.z = f2bf(v.z); o.w = f2bf(v.w);
    *(ushort4*)(xb + i) = o;
}

// ---------- kernel 5: transpose + convert weights ----------
__global__ __launch_bounds__(256) void k_transpose_cvt(
    const float* __restrict__ src, u16* __restrict__ dst, int R, int C)
{
    __shared__ float tile[32][33];
    size_t base = (size_t)blockIdx.z * R * C;
    src += base; dst += base;
    int c0 = blockIdx.x * 32, r0 = blockIdx.y * 32;
    int tx = threadIdx.x & 31, ty = threadIdx.x >> 5;  // 32 x 8
#pragma unroll
    for (int i = 0; i < 32; i += 8)
        tile[ty + i][tx] = src[(size_t)(r0 + ty + i) * C + c0 + tx];
    __syncthreads();
#pragma unroll
    for (int i = 0; i < 32; i += 8)
        dst[(size_t)(c0 + ty + i) * R + r0 + tx] = f2bf(tile[tx][ty + i]);
}

// ---------- kernel 6: fused GEMM1 (W1 and W3 share the A tile) ----------
// 512 threads = 8 waves. Waves 0-3: v1 = Xe@W1^T. Waves 4-7: v3 = Xe@W3^T.
// 2-phase double-buffered prefetch (stage next K-step before computing current).
// Epilogue: LDS exchange of v3 (f32) -> waves 0-3 write h = silu(v1)*v3.
// Grid: 1D linear, tile-fast, chunked XCD swizzle (nwg % 8 == 0).
__global__ __launch_bounds__(512, 4) void k_gemm1f(
    const u16* __restrict__ xb, const u16* __restrict__ w1t,
    const u16* __restrict__ w3t, u16* __restrict__ hbuf,
    const int* __restrict__ pair_token, const int* __restrict__ ctrl)
{
    int ntiles = ctrl[32];
    const int nwg = 32 * MAXTILES;             // 4352, divisible by 8
    int orig = blockIdx.x;
    int w = (orig & 7) * (nwg >> 3) + (orig >> 3);   // XCD-chunked, bijective
    int tile = w % MAXTILES;                   // tile fast within an XCD chunk
    int nblk = w / MAXTILES;
    if (tile >= ntiles) return;
    int e  = ctrl[64 + tile];
    int m0 = ctrl[256 + tile];
    int n0 = nblk * 128;

    const u16* we1 = w1t + (size_t)e * F_DIM * D_DIM;
    const u16* we3 = w3t + (size_t)e * F_DIM * D_DIM;

    __shared__ __align__(16) char smem[49152];
    u16* As  = (u16*)smem;                 // [2][4096] u16 = 16 KiB
    u16* B1s = (u16*)(smem + 16384);       // [2][4096]
    u16* B3s = (u16*)(smem + 32768);       // [2][4096]
    float* ex = (float*)smem;              // epilogue reuse: [2][64*64] f32 = 32 KiB

    int tid  = threadIdx.x;
    int lane = tid & 63, wave = tid >> 6;
    int half = wave >> 2, w4 = wave & 3;   // half 0: W1, half 1: W3
    int wr = w4 >> 1, wc = w4 & 1;
    int quad = lane >> 4, mn = lane & 15;

    // staging: 512 threads, 1 x 16B chunk each of A, B1, B3 per K-step
    int r_s = tid >> 2, kc = tid & 3;      // row 0..127, 16B chunk 0..3
    int tok = pair_token[m0 + r_s];
    const u16* gA  = xb  + (size_t)tok * D_DIM + kc * 8;
    const u16* gB1 = we1 + (size_t)(n0 + r_s) * D_DIM + kc * 8;
    const u16* gB3 = we3 + (size_t)(n0 + r_s) * D_DIM + kc * 8;
    u16* lA  = As  + tid * 8;
    u16* lB1 = B1s + tid * 8;
    u16* lB3 = B3s + tid * 8;

    const u16* Bsel = half ? B3s : B1s;

    f32x4 acc[4][4] = {};

    auto stage = [&](int buf, int k0) {
        gl_lds16(gA  + k0, lA  + buf * 4096);
        gl_lds16(gB1 + k0, lB1 + buf * 4096);
        gl_lds16(gB3 + k0, lB3 + buf * 4096);
    };
    auto compute = [&](int buf) {
        bf16x8 af[4], bfr[4];
#pragma unroll
        for (int i = 0; i < 4; i++)
            af[i] = *(const bf16x8*)(As + buf * 4096 + (wr * 64 + i * 16 + mn) * 32 + quad * 8);
#pragma unroll
        for (int j = 0; j < 4; j++)
            bfr[j] = *(const bf16x8*)(Bsel + buf * 4096 + (wc * 64 + j * 16 + mn) * 32 + quad * 8);
#pragma unroll
        for (int i = 0; i < 4; i++)
#pragma unroll
            for (int j = 0; j < 4; j++)
                acc[i][j] = __builtin_amdgcn_mfma_f32_16x16x32_bf16(af[i], bfr[j], acc[i][j], 0, 0, 0);
    };

    stage(0, 0);
    __syncthreads();                       // drain prologue loads
    int cur = 0;
    for (int k0 = 32; k0 < D_DIM; k0 += 32) {
        stage(cur ^ 1, k0);                // prefetch next K-step (in flight across compute)
        compute(cur);
        __syncthreads();                   // vmcnt(0)+lgkmcnt(0) drain + barrier, once per step
        cur ^= 1;
    }
    compute(cur);
    __syncthreads();                       // LDS about to be reused as exchange buffer

    // epilogue: waves 4-7 hand their v3 quadrant (f32) to waves 0-3 in two rounds
    for (int round = 0; round < 2; round++) {
        if (half == 1 && wr == round) {
            float* exb = ex + (w4 & 1) * 4096;
#pragma unroll
            for (int i = 0; i < 4; i++)
#pragma unroll
                for (int j = 0; j < 4; j++)
#pragma unroll
                    for (int r = 0; r < 4; r++)
                        exb[(i * 16 + quad * 4 + r) * 64 + j * 16 + mn] = acc[i][j][r];
        }
        __syncthreads();
        if (half == 0 && wr == round) {
            const float* exb = ex + (w4 & 1) * 4096;
#pragma unroll
            for (int i = 0; i < 4; i++)
#pragma unroll
                for (int j = 0; j < 4; j++)
#pragma unroll
                    for (int r = 0; r < 4; r++) {
                        float v1 = acc[i][j][r];
                        float v3 = exb[(i * 16 + quad * 4 + r) * 64 + j * 16 + mn];
                        float sl = v1 * (1.f / (1.f + __expf(-v1)));
                        size_t idx = (size_t)(m0 + wr * 64 + i * 16 + quad * 4 + r) * F_DIM
                                   + n0 + wc * 64 + j * 16 + mn;
                        hbuf[idx] = f2bf(sl * v3);
                    }
        }
        __syncthreads();
    }
}

// ---------- kernel 7: GEMM2  out += (h @ W2^T) * w ----------
// 2-phase double-buffered prefetch; 1D tile-fast grid with chunked XCD swizzle:
// each XCD owns one n-block and sweeps consecutive tiles -> its 128-col W2
// panel stays L2-resident; h streams LLC-shared across XCDs.
__global__ __launch_bounds__(256, 4) void k_gemm2(
    const u16* __restrict__ h, const u16* __restrict__ w2t,
    float* __restrict__ out, const int* __restrict__ pair_token,
    const float* __restrict__ pair_w, const int* __restrict__ ctrl)
{
    int ntiles = ctrl[32];
    const int nwg = 8 * MAXTILES;              // 1088, divisible by 8
    int orig = blockIdx.x;
    int w = (orig & 7) * (nwg >> 3) + (orig >> 3);
    int tile = w % MAXTILES;
    int nblk = w / MAXTILES;
    if (tile >= ntiles) return;
    int e  = ctrl[64 + tile];
    int m0 = ctrl[256 + tile];
    int n0 = nblk * 128;

    const u16* w2e = w2t + (size_t)e * D_DIM * F_DIM;

    __shared__ __align__(16) u16 As[2][4096];
    __shared__ __align__(16) u16 Bs[2][4096];

    int tid  = threadIdx.x;
    int lane = tid & 63, wave = tid >> 6;

    int r_a = tid >> 2, kc = tid & 3;
    const u16* gA0 = h   + (size_t)(m0 + r_a) * F_DIM + kc * 8;
    const u16* gA1 = h   + (size_t)(m0 + r_a + 64) * F_DIM + kc * 8;
    const u16* gB0 = w2e + (size_t)(n0 + r_a) * F_DIM + kc * 8;
    const u16* gB1 = w2e + (size_t)(n0 + r_a + 64) * F_DIM + kc * 8;

    int wr = wave >> 1, wc = wave & 1;
    int quad = lane >> 4, mn = lane & 15;

    f32x4 acc[4][4] = {};

    auto stage = [&](int buf, int k0) {
        gl_lds16(gA0 + k0, &As[buf][tid * 8]);
        gl_lds16(gA1 + k0, &As[buf][tid * 8 + 2048]);
        gl_lds16(gB0 + k0, &Bs[buf][tid * 8]);
        gl_lds16(gB1 + k0, &Bs[buf][tid * 8 + 2048]);
    };
    auto compute = [&](int buf) {
        bf16x8 af[4], bfr[4];
#pragma unroll
        for (int i = 0; i < 4; i++)
            af[i] = *(const bf16x8*)(&As[buf][(wr * 64 + i * 16 + mn) * 32 + quad * 8]);
#pragma unroll
        for (int j = 0; j < 4; j++)
            bfr[j] = *(const bf16x8*)(&Bs[buf][(wc * 64 + j * 16 + mn) * 32 + quad * 8]);
#pragma unroll
        for (int i = 0; i < 4; i++)
#pragma unroll
            for (int j = 0; j < 4; j++)
                acc[i][j] = __builtin_amdgcn_mfma_f32_16x16x32_bf16(af[i], bfr[j], acc[i][j], 0, 0, 0);
    };

    stage(0, 0);
    __syncthreads();
    int cur = 0;
    for (int k0 = 32; k0 < F_DIM; k0 += 32) {
        stage(cur ^ 1, k0);
        compute(cur);
        __syncthreads();
        cur ^= 1;
    }
    compute(cur);

#pragma unroll
    for (int i = 0; i < 4; i++)
#pragma unroll
        for (int r = 0; r < 4; r++) {
            int row = wr * 64 + i * 16 + quad * 4 + r;
            int prow = m0 + row;
            int tokv = pair_token[prow];
            float wv = pair_w[prow];
#pragma unroll
            for (int j = 0; j < 4; j++) {
                int col = n0 + wc * 64 + j * 16 + mn;
                atomicAdd(&out[(size_t)tokv * D_DIM + col], acc[i][j][r] * wv);
            }
        }
}

// ---------- launch ----------
extern "C" void kernel_launch(void* const* d_in, const int* in_sizes, int n_in,
                              void* d_out, int out_size, void* d_ws, size_t ws_size,
                              hipStream_t stream)
{
    const float* x      = (const float*)d_in[0];
    const float* gate_w = (const float*)d_in[1];
    const float* W1     = (const float*)d_in[2];
    const float* W3     = (const float*)d_in[3];
    const float* W2     = (const float*)d_in[4];
    float* out = (float*)d_out;
    float* logits_out = out + (size_t)T_TOKENS * D_DIM;

    char* ws = (char*)d_ws;
    int*   ctrl       = (int*)ws;                    // 4096 B (incl tile map)
    int*   pair_token = (int*)(ws + 4096);           // 69632 B
    float* pair_w     = (float*)(ws + 4096 + 69632); // 69632 B
    int*   ti         = (int*)(ws + 143360);         // 65536 B
    float* tw         = (float*)(ws + 208896);       // 65536 B
    u16*   xb         = (u16*)(ws + 1048576);        // 16 MiB
    u16*   w1t        = (u16*)(ws + 17825792);       // 64 MiB
    u16*   w3t        = (u16*)(ws + 84934656);       // 64 MiB
    u16*   w2t        = (u16*)(ws + 152043520);      // 64 MiB
    u16*   h          = (u16*)(ws + 219152384);      // 136 MiB

    hipMemsetAsync(d_out, 0, (size_t)T_TOKENS * D_DIM * sizeof(float), stream);
    hipMemsetAsync(ws, 0, 143360, stream);

    k_router<<<T_TOKENS / 4, 256, 0, stream>>>(x, gate_w, logits_out, ti, tw, ctrl);
    k_plan<<<1, 64, 0, stream>>>(ctrl);
    k_scatter<<<T_TOKENS / 256, 256, 0, stream>>>(ti, tw, ctrl, pair_token, pair_w);

    k_cvt_x<<<(T_TOKENS * D_DIM) / (256 * 4), 256, 0, stream>>>(x, xb);
    dim3 tg1(128, 32, NE);  // W1/W3: R=1024, C=4096
    k_transpose_cvt<<<tg1, 256, 0, stream>>>(W1, w1t, D_DIM, F_DIM);
    k_transpose_cvt<<<tg1, 256, 0, stream>>>(W3, w3t, D_DIM, F_DIM);
    dim3 tg2(32, 128, NE);  // W2: R=4096, C=1024
    k_transpose_cvt<<<tg2, 256, 0, stream>>>(W2, w2t, F_DIM, D_DIM);

    k_gemm1f<<<32 * MAXTILES, 512, 0, stream>>>(xb, w1t, w3t, h, pair_token, ctrl);
    k_gemm2<<<8 * MAXTILES, 256, 0, stream>>>(h, w2t, out, pair_token, pair_w, ctrl);
}

// Round 3
// 1358.195 us; speedup vs baseline: 1.1697x; 1.1697x over previous
//
#include <hip/hip_runtime.h>
#include <hip/hip_bf16.h>
#include <stdint.h>

#define T_TOKENS 8192
#define D_DIM    1024
#define F_DIM    4096
#define NE       8
#define MAXTILES 136

typedef unsigned short u16;
typedef __attribute__((ext_vector_type(8))) __bf16 bf16x8;
typedef __attribute__((ext_vector_type(4))) float  f32x4;

// ---------- helpers ----------
__device__ __forceinline__ u16 f2bf(float f) {
    __hip_bfloat16 h = __float2bfloat16(f);
    return *reinterpret_cast<u16*>(&h);
}

__device__ __forceinline__ float bf2f(u16 r) {
    uint32_t u = ((uint32_t)r) << 16;
    return __uint_as_float(u);
}

__device__ __forceinline__ void gl_lds16(const void* g, void* l) {
    __builtin_amdgcn_global_load_lds(
        (const __attribute__((address_space(1))) uint32_t*)g,
        (__attribute__((address_space(3))) uint32_t*)l, 16, 0, 0);
}

// ---------- ctrl layout (int indices into ws base) ----------
// [0..7] counts  [8..15] cursor  [16..24] off  [32] n_tiles
// [64..199] tile_e  [256..391] tile_m0

// ---------- kernel 1: router ----------
__global__ __launch_bounds__(256) void k_router(
    const float* __restrict__ x, const float* __restrict__ gate_w,
    float* __restrict__ logits_out, int* __restrict__ ti,
    float* __restrict__ tw, int* __restrict__ ctrl)
{
    __shared__ float gw[NE * D_DIM];
    int tid = threadIdx.x;
    for (int i = tid; i < NE * D_DIM; i += 256) gw[i] = gate_w[i];
    __syncthreads();

    int wave = tid >> 6, lane = tid & 63;
    int t = blockIdx.x * 4 + wave;

    const float* xr = x + (size_t)t * D_DIM;
    float xv[16];
#pragma unroll
    for (int i = 0; i < 16; i++) xv[i] = xr[i * 64 + lane];

    float acc[NE];
#pragma unroll
    for (int e = 0; e < NE; e++) {
        float s = 0.f;
#pragma unroll
        for (int i = 0; i < 16; i++) s += xv[i] * gw[e * D_DIM + i * 64 + lane];
        for (int off = 32; off; off >>= 1) s += __shfl_down(s, off, 64);
        acc[e] = s;
    }

    if (lane == 0) {
#pragma unroll
        for (int e = 0; e < NE; e++) logits_out[t * NE + e] = acc[e];
        int i0 = 0; float v0 = acc[0];
        for (int e = 1; e < NE; e++) if (acc[e] > v0) { v0 = acc[e]; i0 = e; }
        int i1 = -1; float v1 = -3.0e38f;
        for (int e = 0; e < NE; e++) if (e != i0 && acc[e] > v1) { v1 = acc[e]; i1 = e; }
        float e1 = expf(v1 - v0);
        float s  = 1.f + e1;
        float w0 = 1.f / s, w1 = e1 / s;
        ti[t * 2 + 0] = i0; ti[t * 2 + 1] = i1;
        tw[t * 2 + 0] = w0; tw[t * 2 + 1] = w1;
        atomicAdd(&ctrl[i0], 1);
        atomicAdd(&ctrl[i1], 1);
    }
}

// ---------- kernel 2: plan ----------
__global__ void k_plan(int* __restrict__ ctrl)
{
    if (threadIdx.x != 0 || blockIdx.x != 0) return;
    int* counts  = ctrl;
    int* off     = ctrl + 16;
    int* tile_e  = ctrl + 64;
    int* tile_m0 = ctrl + 256;
    int o = 0, nt = 0;
    for (int e = 0; e < NE; e++) {
        off[e] = o;
        int c = counts[e];
        int tcnt = (c + 127) >> 7;
        for (int j = 0; j < tcnt; j++) { tile_e[nt] = e; tile_m0[nt] = o + j * 128; nt++; }
        o += tcnt << 7;
    }
    off[NE] = o;
    ctrl[32] = nt;
}

// ---------- kernel 3: scatter ----------
__global__ __launch_bounds__(256) void k_scatter(
    const int* __restrict__ ti, const float* __restrict__ tw,
    int* __restrict__ ctrl, int* __restrict__ pair_token, float* __restrict__ pair_w)
{
    int t = blockIdx.x * 256 + threadIdx.x;
    if (t >= T_TOKENS) return;
    int* off    = ctrl + 16;
    int* cursor = ctrl + 8;
#pragma unroll
    for (int k = 0; k < 2; k++) {
        int e = ti[t * 2 + k];
        int slot = off[e] + atomicAdd(&cursor[e], 1);
        pair_token[slot] = t;
        pair_w[slot] = tw[t * 2 + k];
    }
}

// ---------- kernel 4: x -> bf16 ----------
__global__ __launch_bounds__(256) void k_cvt_x(
    const float* __restrict__ x, u16* __restrict__ xb)
{
    size_t i = ((size_t)blockIdx.x * 256 + threadIdx.x) * 4;
    float4 v = *(const float4*)(x + i);
    ushort4 o;
    o.x = f2bf(v.x); o.y = f2bf(v.y); o.z = f2bf(v.z); o.w = f2bf(v.w);
    *(ushort4*)(xb + i) = o;
}

// ---------- kernel 5: transpose + convert weights ----------
__global__ __launch_bounds__(256) void k_transpose_cvt(
    const float* __restrict__ src, u16* __restrict__ dst, int R, int C)
{
    __shared__ float tile[32][33];
    size_t base = (size_t)blockIdx.z * R * C;
    src += base; dst += base;
    int c0 = blockIdx.x * 32, r0 = blockIdx.y * 32;
    int tx = threadIdx.x & 31, ty = threadIdx.x >> 5;  // 32 x 8
#pragma unroll
    for (int i = 0; i < 32; i += 8)
        tile[ty + i][tx] = src[(size_t)(r0 + ty + i) * C + c0 + tx];
    __syncthreads();
#pragma unroll
    for (int i = 0; i < 32; i += 8)
        dst[(size_t)(c0 + ty + i) * R + r0 + tx] = f2bf(tile[tx][ty + i]);
}

// ---------- kernel 6: fused GEMM1 (W1 and W3 share the A tile) ----------
// 512 threads = 8 waves. Waves 0-3: v1 = Xe@W1^T. Waves 4-7: v3 = Xe@W3^T.
// 2-phase double-buffered prefetch. Epilogue: v3 deposited as bf16 into a
// swizzled LDS tile, silu(v1)*v3 computed in place, then cooperative
// full-line (64B/lane) stores -> no partial-line RMW write amplification.
// Grid: 1D linear, tile-fast, chunked XCD swizzle (nwg % 8 == 0).
__global__ __launch_bounds__(512, 4) void k_gemm1f(
    const u16* __restrict__ xb, const u16* __restrict__ w1t,
    const u16* __restrict__ w3t, u16* __restrict__ hbuf,
    const int* __restrict__ pair_token, const int* __restrict__ ctrl)
{
    int ntiles = ctrl[32];
    const int nwg = 32 * MAXTILES;             // 4352, divisible by 8
    int orig = blockIdx.x;
    int w = (orig & 7) * (nwg >> 3) + (orig >> 3);   // XCD-chunked, bijective
    int tile = w % MAXTILES;                   // tile fast within an XCD chunk
    int nblk = w / MAXTILES;
    if (tile >= ntiles) return;
    int e  = ctrl[64 + tile];
    int m0 = ctrl[256 + tile];
    int n0 = nblk * 128;

    const u16* we1 = w1t + (size_t)e * F_DIM * D_DIM;
    const u16* we3 = w3t + (size_t)e * F_DIM * D_DIM;

    __shared__ __align__(16) char smem[49152];
    u16* As  = (u16*)smem;                 // [2][4096] u16 = 16 KiB
    u16* B1s = (u16*)(smem + 16384);       // [2][4096]
    u16* B3s = (u16*)(smem + 32768);       // [2][4096]

    int tid  = threadIdx.x;
    int lane = tid & 63, wave = tid >> 6;
    int half = wave >> 2, w4 = wave & 3;   // half 0: W1, half 1: W3
    int wr = w4 >> 1, wc = w4 & 1;
    int quad = lane >> 4, mn = lane & 15;

    // staging: 512 threads, 1 x 16B chunk each of A, B1, B3 per K-step
    int r_s = tid >> 2, kc = tid & 3;      // row 0..127, 16B chunk 0..3
    int tok = pair_token[m0 + r_s];
    const u16* gA  = xb  + (size_t)tok * D_DIM + kc * 8;
    const u16* gB1 = we1 + (size_t)(n0 + r_s) * D_DIM + kc * 8;
    const u16* gB3 = we3 + (size_t)(n0 + r_s) * D_DIM + kc * 8;
    u16* lA  = As  + tid * 8;
    u16* lB1 = B1s + tid * 8;
    u16* lB3 = B3s + tid * 8;

    const u16* Bsel = half ? B3s : B1s;

    f32x4 acc[4][4] = {};

    auto stage = [&](int buf, int k0) {
        gl_lds16(gA  + k0, lA  + buf * 4096);
        gl_lds16(gB1 + k0, lB1 + buf * 4096);
        gl_lds16(gB3 + k0, lB3 + buf * 4096);
    };
    auto compute = [&](int buf) {
        bf16x8 af[4], bfr[4];
#pragma unroll
        for (int i = 0; i < 4; i++)
            af[i] = *(const bf16x8*)(As + buf * 4096 + (wr * 64 + i * 16 + mn) * 32 + quad * 8);
#pragma unroll
        for (int j = 0; j < 4; j++)
            bfr[j] = *(const bf16x8*)(Bsel + buf * 4096 + (wc * 64 + j * 16 + mn) * 32 + quad * 8);
#pragma unroll
        for (int i = 0; i < 4; i++)
#pragma unroll
            for (int j = 0; j < 4; j++)
                acc[i][j] = __builtin_amdgcn_mfma_f32_16x16x32_bf16(af[i], bfr[j], acc[i][j], 0, 0, 0);
    };

    stage(0, 0);
    __syncthreads();                       // drain prologue loads
    int cur = 0;
    for (int k0 = 32; k0 < D_DIM; k0 += 32) {
        stage(cur ^ 1, k0);                // prefetch next K-step (in flight across compute)
        compute(cur);
        __syncthreads();                   // vmcnt(0)+lgkmcnt(0) drain + barrier, once per step
        cur ^= 1;
    }
    compute(cur);
    __syncthreads();                       // LDS reads done; reuse smem for h-tile

    // ---- epilogue ----
    // hx: [128][128] bf16 tile (32 KiB), col XOR-swizzled by row for a
    // conflict-free vectorized copy-out.
    u16* hx = (u16*)smem;

    if (half == 1) {                       // deposit v3 (bf16)
#pragma unroll
        for (int i = 0; i < 4; i++)
#pragma unroll
            for (int j = 0; j < 4; j++)
#pragma unroll
                for (int r = 0; r < 4; r++) {
                    int row = wr * 64 + i * 16 + quad * 4 + r;
                    int col = wc * 64 + j * 16 + mn;
                    hx[row * 128 + (col ^ ((row & 7) << 3))] = f2bf(acc[i][j][r]);
                }
    }
    __syncthreads();
    if (half == 0) {                       // h = silu(v1) * v3, in place
#pragma unroll
        for (int i = 0; i < 4; i++)
#pragma unroll
            for (int j = 0; j < 4; j++)
#pragma unroll
                for (int r = 0; r < 4; r++) {
                    int row = wr * 64 + i * 16 + quad * 4 + r;
                    int col = wc * 64 + j * 16 + mn;
                    int ix = row * 128 + (col ^ ((row & 7) << 3));
                    float v3 = bf2f(hx[ix]);
                    float v1 = acc[i][j][r];
                    float sl = v1 * (1.f / (1.f + __expf(-v1)));
                    hx[ix] = f2bf(sl * v3);
                }
    }
    __syncthreads();
    // cooperative copy-out: lane owns one full 64B line (4 x 16B stores)
    {
        int row = tid >> 2, ch = tid & 3;
        u16* dst = hbuf + (size_t)(m0 + row) * F_DIM + n0 + ch * 32;
        const u16* srcrow = hx + row * 128;
        int sw = (row & 7) << 3;
#pragma unroll
        for (int q = 0; q < 4; q++) {
            int col = ch * 32 + q * 8;     // multiple of 8 -> XOR keeps 16B align
            f32x4 v = *(const f32x4*)(srcrow + (col ^ sw));
            *(f32x4*)(dst + q * 8) = v;
        }
    }
}

// ---------- kernel 7: GEMM2  out += (h @ W2^T) * w ----------
// Round-0 proven 2D grid (x = n-block fast, y = tile) + 2-phase prefetch.
__global__ __launch_bounds__(256, 4) void k_gemm2(
    const u16* __restrict__ h, const u16* __restrict__ w2t,
    float* __restrict__ out, const int* __restrict__ pair_token,
    const float* __restrict__ pair_w, const int* __restrict__ ctrl)
{
    int ntiles = ctrl[32];
    int tile = blockIdx.y;
    if (tile >= ntiles) return;
    int e  = ctrl[64 + tile];
    int m0 = ctrl[256 + tile];
    int n0 = blockIdx.x * 128;

    const u16* w2e = w2t + (size_t)e * D_DIM * F_DIM;

    __shared__ __align__(16) u16 As[2][4096];
    __shared__ __align__(16) u16 Bs[2][4096];

    int tid  = threadIdx.x;
    int lane = tid & 63, wave = tid >> 6;

    int r_a = tid >> 2, kc = tid & 3;
    const u16* gA0 = h   + (size_t)(m0 + r_a) * F_DIM + kc * 8;
    const u16* gA1 = h   + (size_t)(m0 + r_a + 64) * F_DIM + kc * 8;
    const u16* gB0 = w2e + (size_t)(n0 + r_a) * F_DIM + kc * 8;
    const u16* gB1 = w2e + (size_t)(n0 + r_a + 64) * F_DIM + kc * 8;

    int wr = wave >> 1, wc = wave & 1;
    int quad = lane >> 4, mn = lane & 15;

    f32x4 acc[4][4] = {};

    auto stage = [&](int buf, int k0) {
        gl_lds16(gA0 + k0, &As[buf][tid * 8]);
        gl_lds16(gA1 + k0, &As[buf][tid * 8 + 2048]);
        gl_lds16(gB0 + k0, &Bs[buf][tid * 8]);
        gl_lds16(gB1 + k0, &Bs[buf][tid * 8 + 2048]);
    };
    auto compute = [&](int buf) {
        bf16x8 af[4], bfr[4];
#pragma unroll
        for (int i = 0; i < 4; i++)
            af[i] = *(const bf16x8*)(&As[buf][(wr * 64 + i * 16 + mn) * 32 + quad * 8]);
#pragma unroll
        for (int j = 0; j < 4; j++)
            bfr[j] = *(const bf16x8*)(&Bs[buf][(wc * 64 + j * 16 + mn) * 32 + quad * 8]);
#pragma unroll
        for (int i = 0; i < 4; i++)
#pragma unroll
            for (int j = 0; j < 4; j++)
                acc[i][j] = __builtin_amdgcn_mfma_f32_16x16x32_bf16(af[i], bfr[j], acc[i][j], 0, 0, 0);
    };

    stage(0, 0);
    __syncthreads();
    int cur = 0;
    for (int k0 = 32; k0 < F_DIM; k0 += 32) {
        stage(cur ^ 1, k0);
        compute(cur);
        __syncthreads();
        cur ^= 1;
    }
    compute(cur);

#pragma unroll
    for (int i = 0; i < 4; i++)
#pragma unroll
        for (int r = 0; r < 4; r++) {
            int row = wr * 64 + i * 16 + quad * 4 + r;
            int prow = m0 + row;
            int tokv = pair_token[prow];
            float wv = pair_w[prow];
#pragma unroll
            for (int j = 0; j < 4; j++) {
                int col = n0 + wc * 64 + j * 16 + mn;
                atomicAdd(&out[(size_t)tokv * D_DIM + col], acc[i][j][r] * wv);
            }
        }
}

// ---------- launch ----------
extern "C" void kernel_launch(void* const* d_in, const int* in_sizes, int n_in,
                              void* d_out, int out_size, void* d_ws, size_t ws_size,
                              hipStream_t stream)
{
    const float* x      = (const float*)d_in[0];
    const float* gate_w = (const float*)d_in[1];
    const float* W1     = (const float*)d_in[2];
    const float* W3     = (const float*)d_in[3];
    const float* W2     = (const float*)d_in[4];
    float* out = (float*)d_out;
    float* logits_out = out + (size_t)T_TOKENS * D_DIM;

    char* ws = (char*)d_ws;
    int*   ctrl       = (int*)ws;                    // 4096 B (incl tile map)
    int*   pair_token = (int*)(ws + 4096);           // 69632 B
    float* pair_w     = (float*)(ws + 4096 + 69632); // 69632 B
    int*   ti         = (int*)(ws + 143360);         // 65536 B
    float* tw         = (float*)(ws + 208896);       // 65536 B
    u16*   xb         = (u16*)(ws + 1048576);        // 16 MiB
    u16*   w1t        = (u16*)(ws + 17825792);       // 64 MiB
    u16*   w3t        = (u16*)(ws + 84934656);       // 64 MiB
    u16*   w2t        = (u16*)(ws + 152043520);      // 64 MiB
    u16*   h          = (u16*)(ws + 219152384);      // 136 MiB

    hipMemsetAsync(d_out, 0, (size_t)T_TOKENS * D_DIM * sizeof(float), stream);
    hipMemsetAsync(ws, 0, 143360, stream);

    k_router<<<T_TOKENS / 4, 256, 0, stream>>>(x, gate_w, logits_out, ti, tw, ctrl);
    k_plan<<<1, 64, 0, stream>>>(ctrl);
    k_scatter<<<T_TOKENS / 256, 256, 0, stream>>>(ti, tw, ctrl, pair_token, pair_w);

    k_cvt_x<<<(T_TOKENS * D_DIM) / (256 * 4), 256, 0, stream>>>(x, xb);
    dim3 tg1(128, 32, NE);  // W1/W3: R=1024, C=4096
    k_transpose_cvt<<<tg1, 256, 0, stream>>>(W1, w1t, D_DIM, F_DIM);
    k_transpose_cvt<<<tg1, 256, 0, stream>>>(W3, w3t, D_DIM, F_DIM);
    dim3 tg2(32, 128, NE);  // W2: R=4096, C=1024
    k_transpose_cvt<<<tg2, 256, 0, stream>>>(W2, w2t, F_DIM, D_DIM);

    k_gemm1f<<<32 * MAXTILES, 512, 0, stream>>>(xb, w1t, w3t, h, pair_token, ctrl);
    dim3 g2(D_DIM / 128, MAXTILES);
    k_gemm2<<<g2, 256, 0, stream>>>(h, w2t, out, pair_token, pair_w, ctrl);
}